// Round 1
// baseline (439.419 us; speedup 1.0000x reference)
//
#include <hip/hip_runtime.h>
#include <hip/hip_bf16.h>

#define N_FEAT 8192
#define SCALING 2.0f   // ALPHA / RANK = 8 / 4
#define EPS 1e-5f

// Kernel 1: per-feature LoRA diag -> scale[i], shift[i]
// A is (N,4) row-major, B is (4,N) row-major.
__global__ __launch_bounds__(256) void lora_diag_kernel(
    const float* __restrict__ sA, const float* __restrict__ sB,
    const float* __restrict__ hA, const float* __restrict__ hB,
    float* __restrict__ scale, float* __restrict__ shift) {
    const int i = blockIdx.x * 256 + threadIdx.x;
    const float4 a1 = ((const float4*)sA)[i];  // A[i, 0..3]
    float s = a1.x * sB[i]
            + a1.y * sB[N_FEAT + i]
            + a1.z * sB[2 * N_FEAT + i]
            + a1.w * sB[3 * N_FEAT + i];
    scale[i] = SCALING * s;
    const float4 a2 = ((const float4*)hA)[i];
    float h = a2.x * hB[i]
            + a2.y * hB[N_FEAT + i]
            + a2.z * hB[2 * N_FEAT + i]
            + a2.w * hB[3 * N_FEAT + i];
    shift[i] = SCALING * h;
}

// Kernel 2: one block (256 threads) per row of N=8192.
// Row cached in registers (8 float4/thread) -> single HBM read of x.
__global__ __launch_bounds__(256) void lora_ln_kernel(
    const float4* __restrict__ x,
    const float* __restrict__ scale, const float* __restrict__ shift,
    float4* __restrict__ out) {
    const int t = threadIdx.x;
    const size_t row = blockIdx.x;
    const float4* xr = x + row * (N_FEAT / 4);

    float4 v[8];
    float s = 0.f, ss = 0.f;
#pragma unroll
    for (int j = 0; j < 8; ++j) {
        v[j] = xr[t + 256 * j];
        s  += v[j].x + v[j].y + v[j].z + v[j].w;
        ss += v[j].x * v[j].x + v[j].y * v[j].y
            + v[j].z * v[j].z + v[j].w * v[j].w;
    }

    // wave (64-lane) reduction
#pragma unroll
    for (int o = 32; o >= 1; o >>= 1) {
        s  += __shfl_down(s, o);
        ss += __shfl_down(ss, o);
    }
    __shared__ float ls[4], lss[4];
    const int wave = t >> 6, lane = t & 63;
    if (lane == 0) { ls[wave] = s; lss[wave] = ss; }
    __syncthreads();
    if (t == 0) {
        const float S  = ls[0] + ls[1] + ls[2] + ls[3];
        const float SS = lss[0] + lss[1] + lss[2] + lss[3];
        const float mean = S * (1.0f / N_FEAT);
        const float var  = SS * (1.0f / N_FEAT) - mean * mean;
        ls[0]  = mean;
        lss[0] = rsqrtf(var + EPS);
    }
    __syncthreads();
    const float mean = ls[0];
    const float rstd = lss[0];

    float4* outr = out + row * (N_FEAT / 4);
    const float4* sc4 = (const float4*)scale;
    const float4* sh4 = (const float4*)shift;
#pragma unroll
    for (int j = 0; j < 8; ++j) {
        const int idx = t + 256 * j;
        const float4 sc = sc4[idx];
        const float4 sh = sh4[idx];
        float4 o;
        o.x = (v[j].x - mean) * rstd * sc.x + sh.x;
        o.y = (v[j].y - mean) * rstd * sc.y + sh.y;
        o.z = (v[j].z - mean) * rstd * sc.z + sh.z;
        o.w = (v[j].w - mean) * rstd * sc.w + sh.w;
        outr[idx] = o;
    }
}

extern "C" void kernel_launch(void* const* d_in, const int* in_sizes, int n_in,
                              void* d_out, int out_size, void* d_ws, size_t ws_size,
                              hipStream_t stream) {
    const float* x  = (const float*)d_in[0];
    const float* sA = (const float*)d_in[1];
    const float* sB = (const float*)d_in[2];
    const float* hA = (const float*)d_in[3];
    const float* hB = (const float*)d_in[4];
    float* out = (float*)d_out;
    float* ws  = (float*)d_ws;   // ws[0..N) = scale, ws[N..2N) = shift

    const int rows = in_sizes[0] / N_FEAT;  // B*S = 8192

    lora_diag_kernel<<<dim3(N_FEAT / 256), dim3(256), 0, stream>>>(
        sA, sB, hA, hB, ws, ws + N_FEAT);
    lora_ln_kernel<<<dim3(rows), dim3(256), 0, stream>>>(
        (const float4*)x, ws, ws + N_FEAT, (float4*)out);
}

// Round 2
// 429.039 us; speedup vs baseline: 1.0242x; 1.0242x over previous
//
#include <hip/hip_runtime.h>
#include <hip/hip_bf16.h>

#define N_FEAT 8192
#define SCALING 2.0f   // ALPHA / RANK = 8 / 4
#define EPS 1e-5f

typedef float floatx4 __attribute__((ext_vector_type(4)));

// Kernel 1: per-feature LoRA diag -> scale[i], shift[i]
// A is (N,4) row-major, B is (4,N) row-major.
__global__ __launch_bounds__(256) void lora_diag_kernel(
    const float* __restrict__ sA, const float* __restrict__ sB,
    const float* __restrict__ hA, const float* __restrict__ hB,
    float* __restrict__ scale, float* __restrict__ shift) {
    const int i = blockIdx.x * 256 + threadIdx.x;
    const floatx4 a1 = ((const floatx4*)sA)[i];  // A[i, 0..3]
    float s = a1.x * sB[i]
            + a1.y * sB[N_FEAT + i]
            + a1.z * sB[2 * N_FEAT + i]
            + a1.w * sB[3 * N_FEAT + i];
    scale[i] = SCALING * s;
    const floatx4 a2 = ((const floatx4*)hA)[i];
    float h = a2.x * hB[i]
            + a2.y * hB[N_FEAT + i]
            + a2.z * hB[2 * N_FEAT + i]
            + a2.w * hB[3 * N_FEAT + i];
    shift[i] = SCALING * h;
}

// Kernel 2: one block (256 threads) per row of N=8192.
// Row cached in registers (8 float4/thread) -> single HBM read of x.
// x / out are streamed once -> non-temporal; scale/shift stay cached.
__global__ __launch_bounds__(256) void lora_ln_kernel(
    const floatx4* __restrict__ x,
    const float* __restrict__ scale, const float* __restrict__ shift,
    floatx4* __restrict__ out) {
    const int t = threadIdx.x;
    const size_t row = blockIdx.x;
    const floatx4* xr = x + row * (N_FEAT / 4);

    floatx4 v[8];
    float s = 0.f, ss = 0.f;
#pragma unroll
    for (int j = 0; j < 8; ++j) {
        v[j] = __builtin_nontemporal_load(xr + t + 256 * j);
        s  += v[j].x + v[j].y + v[j].z + v[j].w;
        ss += v[j].x * v[j].x + v[j].y * v[j].y
            + v[j].z * v[j].z + v[j].w * v[j].w;
    }

    // wave (64-lane) reduction
#pragma unroll
    for (int o = 32; o >= 1; o >>= 1) {
        s  += __shfl_down(s, o);
        ss += __shfl_down(ss, o);
    }
    __shared__ float ls[4], lss[4];
    const int wave = t >> 6, lane = t & 63;
    if (lane == 0) { ls[wave] = s; lss[wave] = ss; }
    __syncthreads();
    if (t == 0) {
        const float S  = ls[0] + ls[1] + ls[2] + ls[3];
        const float SS = lss[0] + lss[1] + lss[2] + lss[3];
        const float mean = S * (1.0f / N_FEAT);
        const float var  = SS * (1.0f / N_FEAT) - mean * mean;
        ls[0]  = mean;
        lss[0] = rsqrtf(var + EPS);
    }
    __syncthreads();
    const float mean = ls[0];
    const float rstd = lss[0];

    floatx4* outr = out + row * (N_FEAT / 4);
    const floatx4* sc4 = (const floatx4*)scale;
    const floatx4* sh4 = (const floatx4*)shift;
#pragma unroll
    for (int j = 0; j < 8; ++j) {
        const int idx = t + 256 * j;
        const floatx4 sc = sc4[idx];   // cached: reused by all 8192 blocks
        const floatx4 sh = sh4[idx];
        floatx4 o;
        o.x = (v[j].x - mean) * rstd * sc.x + sh.x;
        o.y = (v[j].y - mean) * rstd * sc.y + sh.y;
        o.z = (v[j].z - mean) * rstd * sc.z + sh.z;
        o.w = (v[j].w - mean) * rstd * sc.w + sh.w;
        __builtin_nontemporal_store(o, outr + idx);
    }
}

extern "C" void kernel_launch(void* const* d_in, const int* in_sizes, int n_in,
                              void* d_out, int out_size, void* d_ws, size_t ws_size,
                              hipStream_t stream) {
    const float* x  = (const float*)d_in[0];
    const float* sA = (const float*)d_in[1];
    const float* sB = (const float*)d_in[2];
    const float* hA = (const float*)d_in[3];
    const float* hB = (const float*)d_in[4];
    float* out = (float*)d_out;
    float* ws  = (float*)d_ws;   // ws[0..N) = scale, ws[N..2N) = shift

    const int rows = in_sizes[0] / N_FEAT;  // B*S = 8192

    lora_diag_kernel<<<dim3(N_FEAT / 256), dim3(256), 0, stream>>>(
        sA, sB, hA, hB, ws, ws + N_FEAT);
    lora_ln_kernel<<<dim3(rows), dim3(256), 0, stream>>>(
        (const floatx4*)x, ws, ws + N_FEAT, (floatx4*)out);
}